// Round 4
// baseline (108.768 us; speedup 1.0000x reference)
//
#include <hip/hip_runtime.h>

// BurstNeuron forward @ t==0, spike_mode=True, burst=True.
//
// Derivation (round 0): the reference's global reduction n_global never binds:
//   spike = min(k1, n_global, T)*th == min(k1, T)*th.
// Pure elementwise: mem0 = th/2 + x; k1 = mem0>th ? ceil((mem0-th)/th) : 0;
// out = min(k1, T)*th.  Memory-bound: 256 MiB in + 256 MiB out, single touch
// each -> non-temporal streams; 16 KB threshold stays cached.
// Exact IEEE division kept (no fast-math, no rcp) so ceil() matches the np
// reference bit-exactly (absmax 0.0 in rounds 1 and 3).
//
// Round-4 changes:
//  * threshold load hoisted out of the loop: stride = grid*block = 524288 is a
//    multiple of cvec = 1024, so (i + k*stride) & cmask is loop-invariant.
//    (host guarantees grid*block % cvec == 0)
//  * 4x-unrolled grid-stride loop: 4 independent nt-load -> compute -> nt-store
//    chains per iteration for memory-level parallelism.

typedef float vfloat4 __attribute__((ext_vector_type(4)));

__global__ __launch_bounds__(256) void burst_neuron_kernel(
    const vfloat4* __restrict__ x,
    const vfloat4* __restrict__ th4,
    const int* __restrict__ Tp,
    vfloat4* __restrict__ out,
    int nvec,          // total float4 count
    int cmask)         // (C/4 - 1), C/4 is a power of two
{
    const float Tf = (float)(*Tp);
    const int stride = gridDim.x * blockDim.x;
    const int i0 = blockIdx.x * blockDim.x + threadIdx.x;

    // Loop-invariant per-channel threshold (stride % (cmask+1) == 0).
    const vfloat4 tv = th4[i0 & cmask];

    #define BN_ALL(o, xv)                                           \
    {                                                               \
        for (int c = 0; c < 4; ++c) {                               \
            const float t   = tv[c];                                \
            const float mem = t * 0.5f + xv[c];                     \
            float k = (mem > t) ? ceilf((mem - t) / t) : 0.0f;      \
            o[c] = fminf(k, Tf) * t;                                \
        }                                                           \
    }

    int i = i0;
    // 4x-unrolled main loop (nvec/stride = 32 at the launch config -> 8 iters,
    // no tail; tail loop kept for safety).
    for (; i + 3 * stride < nvec; i += 4 * stride) {
        const vfloat4 xa = __builtin_nontemporal_load(&x[i]);
        const vfloat4 xb = __builtin_nontemporal_load(&x[i + stride]);
        const vfloat4 xc = __builtin_nontemporal_load(&x[i + 2 * stride]);
        const vfloat4 xd = __builtin_nontemporal_load(&x[i + 3 * stride]);
        vfloat4 oa, ob, oc, od;
        BN_ALL(oa, xa)
        BN_ALL(ob, xb)
        BN_ALL(oc, xc)
        BN_ALL(od, xd)
        __builtin_nontemporal_store(oa, &out[i]);
        __builtin_nontemporal_store(ob, &out[i + stride]);
        __builtin_nontemporal_store(oc, &out[i + 2 * stride]);
        __builtin_nontemporal_store(od, &out[i + 3 * stride]);
    }
    for (; i < nvec; i += stride) {
        const vfloat4 xa = __builtin_nontemporal_load(&x[i]);
        vfloat4 oa;
        BN_ALL(oa, xa)
        __builtin_nontemporal_store(oa, &out[i]);
    }

    #undef BN_ALL
}

extern "C" void kernel_launch(void* const* d_in, const int* in_sizes, int n_in,
                              void* d_out, int out_size, void* d_ws, size_t ws_size,
                              hipStream_t stream) {
    const vfloat4* x   = (const vfloat4*)d_in[0];
    const vfloat4* th4 = (const vfloat4*)d_in[1];
    const int*     Tp  = (const int*)d_in[2];
    vfloat4*       out = (vfloat4*)d_out;

    const int nvec  = in_sizes[0] / 4;        // 16,777,216
    const int cvec  = in_sizes[1] / 4;        // 1024 (power of two)
    const int cmask = cvec - 1;

    const int block = 256;
    int grid = (nvec + block - 1) / block;
    if (grid > 2048) grid = 2048;             // 8 blocks/CU, grid-stride the rest
    // Threshold-hoist validity: stride must be a multiple of cvec.
    // grid*block = 524288, cvec = 1024 -> holds. (If a different shape ever
    // violated this, round grid down to a multiple of cvec/block.)

    burst_neuron_kernel<<<grid, block, 0, stream>>>(x, th4, Tp, out, nvec, cmask);
}

// Round 5
// 86.289 us; speedup vs baseline: 1.2605x; 1.2605x over previous
//
#include <hip/hip_runtime.h>

// BurstNeuron forward @ t==0, spike_mode=True, burst=True.
//
// Derivation (round 0): the reference's global reduction n_global never binds:
//   spike = min(k1, n_global, T)*th == min(k1, T)*th.
// Pure elementwise: mem0 = th/2 + x; k1 = mem0>th ? ceil((mem0-th)/th) : 0;
// out = min(k1, T)*th.  Memory-bound: 256 MiB in + 256 MiB out, single touch
// each -> non-temporal streams; 16 KB threshold stays L1/L2-cached.
// Exact IEEE division kept (no fast-math, no rcp) so ceil() matches the np
// reference bit-exactly (absmax 0.0 in rounds 1/3/4).
//
// Round-5 change: drop the grid-stride loop entirely -> one float4 per thread
// (grid*block == nvec exactly). Memory-level parallelism comes from wave-level
// TLP (32 waves/CU of independent load->store chains, waves retire as soon as
// their store issues) instead of in-thread unrolling, which round 4 showed to
// be counterproductive (103.2 -> 108.8 us at 4x).

typedef float vfloat4 __attribute__((ext_vector_type(4)));

__global__ __launch_bounds__(256) void burst_neuron_kernel(
    const vfloat4* __restrict__ x,
    const vfloat4* __restrict__ th4,
    const int* __restrict__ Tp,
    vfloat4* __restrict__ out,
    int nvec,          // total float4 count
    int cmask)         // (C/4 - 1), C/4 is a power of two
{
    const int i = blockIdx.x * blockDim.x + threadIdx.x;
    if (i >= nvec) return;

    const float Tf = (float)(*Tp);
    const vfloat4 xv = __builtin_nontemporal_load(&x[i]);
    const vfloat4 tv = th4[i & cmask];   // per-channel threshold, cache-resident

    vfloat4 o;
    for (int c = 0; c < 4; ++c) {
        const float t   = tv[c];
        const float mem = t * 0.5f + xv[c];
        float k = (mem > t) ? ceilf((mem - t) / t) : 0.0f;
        o[c] = fminf(k, Tf) * t;
    }

    __builtin_nontemporal_store(o, &out[i]);
}

extern "C" void kernel_launch(void* const* d_in, const int* in_sizes, int n_in,
                              void* d_out, int out_size, void* d_ws, size_t ws_size,
                              hipStream_t stream) {
    const vfloat4* x   = (const vfloat4*)d_in[0];
    const vfloat4* th4 = (const vfloat4*)d_in[1];
    const int*     Tp  = (const int*)d_in[2];
    vfloat4*       out = (vfloat4*)d_out;

    const int nvec  = in_sizes[0] / 4;        // 16,777,216
    const int cvec  = in_sizes[1] / 4;        // 1024 (power of two)
    const int cmask = cvec - 1;

    const int block = 256;
    const int grid  = (nvec + block - 1) / block;   // 65536 blocks, 1 vec4/thread

    burst_neuron_kernel<<<grid, block, 0, stream>>>(x, th4, Tp, out, nvec, cmask);
}